// Round 2
// baseline (255.134 us; speedup 1.0000x reference)
//
#include <hip/hip_runtime.h>
#include <stdint.h>

// Problem constants (reference file)
#define B_SZ 16
#define L_SZ 1024
#define D_SZ 512
#define E_SZ 8
#define DFF_SZ 2048

typedef short bf16x8 __attribute__((ext_vector_type(8)));
typedef float f32x4 __attribute__((ext_vector_type(4)));

__device__ __forceinline__ unsigned short f2bf(float f) {
  unsigned int u = __float_as_uint(f);
  u += 0x7fffu + ((u >> 16) & 1u);   // round-to-nearest-even
  return (unsigned short)(u >> 16);
}

__device__ __forceinline__ void async_cp16(void* lds, const void* g) {
  __builtin_amdgcn_global_load_lds(
      (const __attribute__((address_space(1))) void*)g,
      (__attribute__((address_space(3))) void*)lds, 16, 0, 0);
}

// ---------------------------------------------------------------------------
// Kernel 1: router — top1 per sample + balance loss
// ---------------------------------------------------------------------------
__global__ void router_kernel(const int* __restrict__ view_ids,
                              const int* __restrict__ visit_ids,
                              const float* __restrict__ rview,
                              const float* __restrict__ rvisit,
                              int* __restrict__ top1,
                              float* __restrict__ loss_out) {
  __shared__ float probs[B_SZ][E_SZ];
  const int t = threadIdx.x;
  if (t < B_SZ) {
    const int vi = view_ids[t];
    const int si = visit_ids[t];
    float lg[E_SZ];
#pragma unroll
    for (int e = 0; e < E_SZ; ++e)
      lg[e] = rview[vi * E_SZ + e] + rvisit[si * E_SZ + e];
    int am = 0;
    float bm = lg[0];
#pragma unroll
    for (int e = 1; e < E_SZ; ++e)
      if (lg[e] > bm) { bm = lg[e]; am = e; }
    top1[t] = am;
    float s = 0.f;
#pragma unroll
    for (int e = 0; e < E_SZ; ++e) {
      const float p = expf(lg[e] - bm);
      probs[t][e] = p;
      s += p;
    }
    const float inv = 1.f / s;
#pragma unroll
    for (int e = 0; e < E_SZ; ++e) probs[t][e] *= inv;
  }
  __syncthreads();
  if (t == 0) {
    float loss = 0.f;
#pragma unroll
    for (int e = 0; e < E_SZ; ++e) {
      float ld = 0.f;
      for (int b = 0; b < B_SZ; ++b) ld += probs[b][e];
      ld *= (1.0f / B_SZ);
      loss -= ld * logf(ld);
    }
    *loss_out = loss;
  }
}

// ---------------------------------------------------------------------------
// Kernel 2: cast x fp32 -> bf16, vectorized float4 -> ushort4
// ---------------------------------------------------------------------------
__global__ void cast_x_kernel(const float* __restrict__ x,
                              unsigned short* __restrict__ xb) {
  const int i = blockIdx.x * 256 + threadIdx.x;
  const float4 v = reinterpret_cast<const float4*>(x)[i];
  ushort4 o;
  o.x = f2bf(v.x); o.y = f2bf(v.y); o.z = f2bf(v.z); o.w = f2bf(v.w);
  reinterpret_cast<ushort4*>(xb)[i] = o;
}

// ---------------------------------------------------------------------------
// Kernel 3: transpose + cast: src [E][K][N] fp32 -> dst [E][N][K] bf16
// ---------------------------------------------------------------------------
__global__ void transpose_cast_kernel(const float* __restrict__ src,
                                      unsigned short* __restrict__ dst,
                                      int K, int N) {
  __shared__ float tile[64][65];
  const int e = blockIdx.z;
  const int n0 = blockIdx.x * 64;
  const int k0 = blockIdx.y * 64;
  const int t = threadIdx.x;
  const int c = t & 63;
  const int r4 = t >> 6;
  const float* s = src + ((size_t)e * K + k0) * N + n0;
#pragma unroll
  for (int it = 0; it < 16; ++it) {
    const int k = it * 4 + r4;
    tile[k][c] = s[(size_t)k * N + c];
  }
  __syncthreads();
  unsigned short* d = dst + ((size_t)e * N + n0) * K + k0;
#pragma unroll
  for (int it = 0; it < 16; ++it) {
    const int n = it * 4 + r4;
    d[(size_t)n * K + c] = f2bf(tile[c][n]);
  }
}

// ---------------------------------------------------------------------------
// Kernel 4: grouped bf16 MFMA GEMM — 8-phase schedule (T2+T3+T4+T5, m201-style)
//   Block tile 256 x BN, BK=64, 512 threads = 8 waves.
//   LDS: 2 dbuf x { A: 2 halves x 128x64, B: 2 halves x (BN/2)x64 } bf16,
//        XOR-swizzled granules (both-sides: pre-swizzled global src + swz read).
//   Phase (qm,qn): block-quadrant 128 x BN/2 over K=64:
//     {12 ds_read_b128 | stage 1 half-tile | s_barrier | 16 MFMA (setprio 1)
//      | [counted vmcnt at phase 3] | s_barrier}
//   Stage schedule per K-tile t: p0->A1(t+1), p1->B1(t+1),
//     p2->A0(t+2) (slot dead after p1), p3->B0(t+2) (dead after p2).
//   Boundary wait: vmcnt(LA+LB) (=4 or 3) — loads for K-tile t+2 stay in
//   flight across the barrier; vmcnt(0) only at the tail.
// ---------------------------------------------------------------------------
template <int BN, int WN2, int NTILES, bool RELU, bool OUT_BF16>
__global__ __launch_bounds__(512, 2) void gemm8_kernel(
    const unsigned short* __restrict__ A,
    const unsigned short* __restrict__ BT,
    const float* __restrict__ bias,
    const int* __restrict__ top1,
    void* __restrict__ Out,
    int N, int K) {
  constexpr int HB = BN / 2;          // rows per B half
  constexpr int WM2 = 8 / WN2;        // wave grid inside a quadrant
  constexpr int RPA = 128 / WM2;      // A rows per wave in quadrant
  constexpr int RPB = HB / WN2;       // B rows per wave in quadrant
  constexpr int MF = RPA / 16;        // m fragments per wave per quadrant
  constexpr int NF = RPB / 16;        // n fragments
  constexpr int LB = HB / 64;         // global_load_lds per B half (A: 2)
  constexpr int ABUF = 2 * 128 * 64;  // elems (A region per buf)
  constexpr int BBUF = 2 * HB * 64;
  constexpr int BUFSZ = ABUF + BBUF;

  __shared__ __align__(16) unsigned short sm[2 * BUFSZ];

  const int t = threadIdx.x;
  const int lane = t & 63;
  const int wid = t >> 6;
  const int wm2 = wid / WN2;
  const int wn2 = wid % WN2;
  const int lr = lane & 15, lg = lane >> 4;

  // block mapping + XCD-aware swizzle (nwg % 8 == 0 in both instantiations)
  const int nwg = gridDim.x;
  const int bid = blockIdx.x;
  const int wg = (bid & 7) * (nwg >> 3) + (bid >> 3);
  const int mt = wg / NTILES;          // m-tile over B*L/256 = 64
  const int nt = wg % NTILES;
  const int n0 = nt * BN;
  const int bz = mt >> 2;              // 1024 rows per sample / 256
  const int e = top1[bz];

  // staging source: thread t owns granule (row = t>>3, g = t&7); the source
  // granule is pre-swizzled so linear global_load_lds + swizzled ds_read match
  const size_t Kb = (size_t)K * 2;
  const int srow = t >> 3;                       // 0..63
  const int sgr = (t & 7) ^ (srow & 7);          // (row+64)&7 == row&7
  const char* aRow = (const char*)A + ((size_t)mt * 256 + srow) * Kb + sgr * 16;
  const char* bRow =
      (const char*)BT + ((size_t)e * N + n0 + srow) * Kb + sgr * 16;

  auto stageA = [&](int buf, int half, int kt) {
    char* dst = (char*)sm + (size_t)(buf * BUFSZ + half * (128 * 64)) * 2 + t * 16;
    const char* s = aRow + (size_t)(half * 128) * Kb + (size_t)kt * 128;
    async_cp16(dst, s);
    async_cp16(dst + 8192, s + 64 * Kb);
  };
  auto stageB = [&](int buf, int half, int kt) {
    char* dst =
        (char*)sm + (size_t)(buf * BUFSZ + ABUF + half * (HB * 64)) * 2 + t * 16;
    const char* s = bRow + (size_t)(half * HB) * Kb + (size_t)kt * 128;
    async_cp16(dst, s);
    if constexpr (LB == 2) async_cp16(dst + 8192, s + 64 * Kb);
  };

  f32x4 acc[2][2][MF][NF] = {};
  const int nk = K >> 6;

  // prologue: K-tile 0 complete + A0,B0 of K-tile 1; keep 2 half-tiles in flight
  stageA(0, 0, 0); stageB(0, 0, 0); stageA(0, 1, 0); stageB(0, 1, 0);
  stageA(1, 0, 1); stageB(1, 0, 1);
  if constexpr (LB == 2) asm volatile("s_waitcnt vmcnt(4)" ::: "memory");
  else                   asm volatile("s_waitcnt vmcnt(3)" ::: "memory");
  __builtin_amdgcn_s_barrier();
  asm volatile("" ::: "memory");

#define PHASE(QM, QN, STAGE_STMT, TAIL_STMT)                                   \
  {                                                                            \
    const char* ab =                                                           \
        (const char*)sm + (size_t)(bi * BUFSZ + (QM) * (128 * 64)) * 2;        \
    const char* bbp =                                                          \
        (const char*)sm + (size_t)(bi * BUFSZ + ABUF + (QN) * (HB * 64)) * 2;  \
    bf16x8 af[MF][2], bg[NF][2];                                               \
    _Pragma("unroll") for (int mf = 0; mf < MF; ++mf) {                        \
      const int row = wm2 * RPA + mf * 16 + lr;                                \
      _Pragma("unroll") for (int ks = 0; ks < 2; ++ks)                         \
          af[mf][ks] = *(const bf16x8*)(ab + row * 128 +                       \
                                        (((ks * 4 + lg) ^ (lr & 7)) << 4));    \
    }                                                                          \
    _Pragma("unroll") for (int nf = 0; nf < NF; ++nf) {                        \
      const int row = wn2 * RPB + nf * 16 + lr;                                \
      _Pragma("unroll") for (int ks = 0; ks < 2; ++ks)                         \
          bg[nf][ks] = *(const bf16x8*)(bbp + row * 128 +                      \
                                        (((ks * 4 + lg) ^ (lr & 7)) << 4));    \
    }                                                                          \
    STAGE_STMT                                                                 \
    __builtin_amdgcn_s_barrier();                                              \
    asm volatile("" ::: "memory");                                             \
    __builtin_amdgcn_s_setprio(1);                                             \
    _Pragma("unroll") for (int ks = 0; ks < 2; ++ks)                           \
        _Pragma("unroll") for (int mf = 0; mf < MF; ++mf)                      \
            _Pragma("unroll") for (int nf = 0; nf < NF; ++nf)                  \
                acc[QM][QN][mf][nf] = __builtin_amdgcn_mfma_f32_16x16x32_bf16( \
                    af[mf][ks], bg[nf][ks], acc[QM][QN][mf][nf], 0, 0, 0);     \
    __builtin_amdgcn_s_setprio(0);                                             \
    TAIL_STMT                                                                  \
    __builtin_amdgcn_s_barrier();                                              \
    asm volatile("" ::: "memory");                                             \
  }

  for (int kt = 0; kt < nk; ++kt) {
    const int bi = kt & 1;
    PHASE(0, 0, { if (kt + 1 < nk) stageA(bi ^ 1, 1, kt + 1); }, {})
    PHASE(0, 1, { if (kt + 1 < nk) stageB(bi ^ 1, 1, kt + 1); }, {})
    PHASE(1, 0, { if (kt + 2 < nk) stageA(bi, 0, kt + 2); }, {})
    PHASE(1, 1, { if (kt + 2 < nk) stageB(bi, 0, kt + 2); },
          {
            if (kt + 2 < nk) {
              if constexpr (LB == 2)
                asm volatile("s_waitcnt vmcnt(4)" ::: "memory");
              else
                asm volatile("s_waitcnt vmcnt(3)" ::: "memory");
            } else {
              asm volatile("s_waitcnt vmcnt(0)" ::: "memory");
            }
          })
  }
#undef PHASE

  // epilogue — C/D mapping col=lane&15, row=(lane>>4)*4+reg (m89-verified)
  const size_t mrow0 = (size_t)mt * 256;
  const float* bp = bias + (size_t)e * N + n0;
  unsigned short* ho = (unsigned short*)Out;
  float* fo = (float*)Out;
#pragma unroll
  for (int qm = 0; qm < 2; ++qm)
#pragma unroll
    for (int mf = 0; mf < MF; ++mf) {
      const int row0 = qm * 128 + wm2 * RPA + mf * 16 + lg * 4;
#pragma unroll
      for (int qn = 0; qn < 2; ++qn)
#pragma unroll
        for (int nf = 0; nf < NF; ++nf) {
          const int col = qn * HB + wn2 * RPB + nf * 16 + lr;
          const float bv = bp[col];
#pragma unroll
          for (int r = 0; r < 4; ++r) {
            float v = acc[qm][qn][mf][nf][r] + bv;
            if (RELU) v = fmaxf(v, 0.f);
            const size_t o = (mrow0 + row0 + r) * (size_t)N + n0 + col;
            if (OUT_BF16) ho[o] = f2bf(v);
            else fo[o] = v;
          }
        }
    }
}

// ---------------------------------------------------------------------------
// Launch
// ---------------------------------------------------------------------------
extern "C" void kernel_launch(void* const* d_in, const int* in_sizes, int n_in,
                              void* d_out, int out_size, void* d_ws,
                              size_t ws_size, hipStream_t stream) {
  const float* x = (const float*)d_in[0];
  const int* view_ids = (const int*)d_in[1];
  const int* visit_ids = (const int*)d_in[2];
  const float* rview = (const float*)d_in[3];
  const float* rvisit = (const float*)d_in[4];
  const float* W1 = (const float*)d_in[5];
  const float* b1 = (const float*)d_in[6];
  const float* W2 = (const float*)d_in[7];
  const float* b2 = (const float*)d_in[8];
  float* out = (float*)d_out;

  char* ws = (char*)d_ws;
  int* top1 = (int*)ws;                                               //    64 B
  unsigned short* x_bf = (unsigned short*)(ws + 256);                 // 16 MiB
  unsigned short* w1t = (unsigned short*)(ws + 256 + 16777216L);      // 16 MiB
  unsigned short* w2t = (unsigned short*)(ws + 256 + 2 * 16777216L);  // 16 MiB
  unsigned short* h_bf = (unsigned short*)(ws + 256 + 3 * 16777216L); // 64 MiB

  router_kernel<<<1, 64, 0, stream>>>(view_ids, visit_ids, rview, rvisit, top1,
                                      out + (size_t)B_SZ * L_SZ * D_SZ);
  cast_x_kernel<<<8192, 256, 0, stream>>>(x, x_bf);
  transpose_cast_kernel<<<dim3(DFF_SZ / 64, D_SZ / 64, E_SZ), 256, 0, stream>>>(
      W1, w1t, D_SZ, DFF_SZ);
  transpose_cast_kernel<<<dim3(D_SZ / 64, DFF_SZ / 64, E_SZ), 256, 0, stream>>>(
      W2, w2t, DFF_SZ, D_SZ);

  // GEMM1: h = relu(x @ W1[e] + b1[e]) -> bf16.  M=16384, N=2048, K=512.
  // 256x256 tiles: 64 x 8 = 512 blocks.
  gemm8_kernel<256, 4, 8, true, true><<<512, 512, 0, stream>>>(
      x_bf, w1t, b1, top1, (void*)h_bf, DFF_SZ, D_SZ);
  // GEMM2: out = h @ W2[e] + b2[e] -> f32.  M=16384, N=512, K=2048.
  // 256x128 tiles: 64 x 4 = 256 blocks (exactly 1 per CU).
  gemm8_kernel<128, 2, 4, false, false><<<256, 512, 0, stream>>>(
      h_bf, w2t, b2, top1, (void*)out, D_SZ, DFF_SZ);
}

// Round 3
// 245.257 us; speedup vs baseline: 1.0403x; 1.0403x over previous
//
#include <hip/hip_runtime.h>
#include <stdint.h>

// Problem constants (reference file)
#define B_SZ 16
#define L_SZ 1024
#define D_SZ 512
#define E_SZ 8
#define DFF_SZ 2048

typedef short bf16x8 __attribute__((ext_vector_type(8)));
typedef float f32x4 __attribute__((ext_vector_type(4)));

__device__ __forceinline__ unsigned short f2bf(float f) {
  unsigned int u = __float_as_uint(f);
  u += 0x7fffu + ((u >> 16) & 1u);   // round-to-nearest-even
  return (unsigned short)(u >> 16);
}

__device__ __forceinline__ void async_cp16(void* lds, const void* g) {
  __builtin_amdgcn_global_load_lds(
      (const __attribute__((address_space(1))) void*)g,
      (__attribute__((address_space(3))) void*)lds, 16, 0, 0);
}

// ---------------------------------------------------------------------------
// Kernel 1: router — top1 per sample + balance loss
// ---------------------------------------------------------------------------
__global__ void router_kernel(const int* __restrict__ view_ids,
                              const int* __restrict__ visit_ids,
                              const float* __restrict__ rview,
                              const float* __restrict__ rvisit,
                              int* __restrict__ top1,
                              float* __restrict__ loss_out) {
  __shared__ float probs[B_SZ][E_SZ];
  const int t = threadIdx.x;
  if (t < B_SZ) {
    const int vi = view_ids[t];
    const int si = visit_ids[t];
    float lg[E_SZ];
#pragma unroll
    for (int e = 0; e < E_SZ; ++e)
      lg[e] = rview[vi * E_SZ + e] + rvisit[si * E_SZ + e];
    int am = 0;
    float bm = lg[0];
#pragma unroll
    for (int e = 1; e < E_SZ; ++e)
      if (lg[e] > bm) { bm = lg[e]; am = e; }
    top1[t] = am;
    float s = 0.f;
#pragma unroll
    for (int e = 0; e < E_SZ; ++e) {
      const float p = expf(lg[e] - bm);
      probs[t][e] = p;
      s += p;
    }
    const float inv = 1.f / s;
#pragma unroll
    for (int e = 0; e < E_SZ; ++e) probs[t][e] *= inv;
  }
  __syncthreads();
  if (t == 0) {
    float loss = 0.f;
#pragma unroll
    for (int e = 0; e < E_SZ; ++e) {
      float ld = 0.f;
      for (int b = 0; b < B_SZ; ++b) ld += probs[b][e];
      ld *= (1.0f / B_SZ);
      loss -= ld * logf(ld);
    }
    *loss_out = loss;
  }
}

// ---------------------------------------------------------------------------
// Kernel 2: cast x fp32 -> bf16, vectorized float4 -> ushort4
// ---------------------------------------------------------------------------
__global__ void cast_x_kernel(const float* __restrict__ x,
                              unsigned short* __restrict__ xb) {
  const int i = blockIdx.x * 256 + threadIdx.x;
  const float4 v = reinterpret_cast<const float4*>(x)[i];
  ushort4 o;
  o.x = f2bf(v.x); o.y = f2bf(v.y); o.z = f2bf(v.z); o.w = f2bf(v.w);
  reinterpret_cast<ushort4*>(xb)[i] = o;
}

// ---------------------------------------------------------------------------
// Kernel 3: transpose + cast: src [E][K][N] fp32 -> dst [E][N][K] bf16
// float4 loads / ushort4 stores; pad-65 LDS => 2-way conflicts only (free).
// ---------------------------------------------------------------------------
__global__ void transpose_cast_kernel(const float* __restrict__ src,
                                      unsigned short* __restrict__ dst,
                                      int K, int N) {
  __shared__ float tile[64][65];
  const int e = blockIdx.z;
  const int n0 = blockIdx.x * 64;
  const int k0 = blockIdx.y * 64;
  const int t = threadIdx.x;          // 256
  {
    const int c4 = (t & 15) * 4;      // n within tile
    const int r = t >> 4;             // 0..15
    const float* s = src + ((size_t)e * K + k0) * N + n0;
#pragma unroll
    for (int i = 0; i < 4; ++i) {
      const int k = r + i * 16;
      const float4 v = *(const float4*)(s + (size_t)k * N + c4);
      tile[k][c4] = v.x; tile[k][c4 + 1] = v.y;
      tile[k][c4 + 2] = v.z; tile[k][c4 + 3] = v.w;
    }
  }
  __syncthreads();
  {
    const int k4 = (t & 15) * 4;      // k within tile
    const int r = t >> 4;
    unsigned short* d = dst + ((size_t)e * N + n0) * K + k0;
#pragma unroll
    for (int i = 0; i < 4; ++i) {
      const int n = r + i * 16;
      ushort4 o;
      o.x = f2bf(tile[k4 + 0][n]); o.y = f2bf(tile[k4 + 1][n]);
      o.z = f2bf(tile[k4 + 2][n]); o.w = f2bf(tile[k4 + 3][n]);
      *(ushort4*)(d + (size_t)n * K + k4) = o;
    }
  }
}

// ---------------------------------------------------------------------------
// Kernel 4: grouped bf16 MFMA GEMM — 8-phase, register-fragment-reuse variant.
//   Block tile 256 x BN, BK=64, 512 threads = 8 waves (WM2 x WN2 per quadrant).
//   Per K-tile, each fragment is ds_read ONCE (24 reads/wave for GEMM1 vs 48
//   in round 2 — LDS-read redundancy was the diagnosed 23%-MfmaUtil limiter):
//     P0: read A0,B0 | stage A1(t+1) | bar | MMA(0,0) | bar
//     P1: read B1    | stage B1(t+1) | bar | MMA(0,1) [af regs reused] | bar
//     P2: read A1    | stage A0(t+2) | bar | MMA(1,0) [bg0 regs reused]| bar
//     P3: (no reads) | stage B0(t+2) | bar | MMA(1,1) | vmcnt(cnt) | bar
//   Counted vmcnt once per K-tile (loads for t+2 stay in flight); vmcnt(0)
//   only in the drain tail. ds_read completion handled by compiler's
//   fine-grained lgkmcnt (first MFMA starts when its frags arrive).
// ---------------------------------------------------------------------------
template <int BN, int WN2, int NTILES, bool RELU, bool OUT_BF16>
__global__ __launch_bounds__(512, 2) void gemm8_kernel(
    const unsigned short* __restrict__ A,
    const unsigned short* __restrict__ BT,
    const float* __restrict__ bias,
    const int* __restrict__ top1,
    void* __restrict__ Out,
    int N, int K) {
  constexpr int HB = BN / 2;          // rows per B half
  constexpr int WM2 = 8 / WN2;        // wave grid inside a quadrant
  constexpr int RPA = 128 / WM2;      // A rows per wave in quadrant
  constexpr int RPB = HB / WN2;       // B rows per wave in quadrant
  constexpr int MF = RPA / 16;        // m fragments per wave per quadrant
  constexpr int NF = RPB / 16;        // n fragments
  constexpr int LB = HB / 64;         // global_load_lds per B half (A: 2)
  constexpr int ABUF = 2 * 128 * 64;  // elems (A region per buf)
  constexpr int BBUF = 2 * HB * 64;
  constexpr int BUFSZ = ABUF + BBUF;

  __shared__ __align__(16) unsigned short sm[2 * BUFSZ];

  const int t = threadIdx.x;
  const int lane = t & 63;
  const int wid = t >> 6;
  const int wm2 = wid / WN2;
  const int wn2 = wid % WN2;
  const int lr = lane & 15, lg = lane >> 4;

  // block mapping + XCD-aware swizzle (nwg % 8 == 0 in both instantiations)
  const int nwg = gridDim.x;
  const int bid = blockIdx.x;
  const int wg = (bid & 7) * (nwg >> 3) + (bid >> 3);
  const int mt = wg / NTILES;          // m-tile over B*L/256 = 64
  const int nt = wg % NTILES;
  const int n0 = nt * BN;
  const int bz = mt >> 2;              // 1024 rows per sample / 256
  const int e = top1[bz];

  // staging: thread t owns granule (row=t>>3, g=t&7); source granule is
  // pre-swizzled (g ^ row&7) so linear global_load_lds + swizzled ds_read match
  const size_t Kb = (size_t)K * 2;
  const int srow = t >> 3;                       // 0..63
  const int sgr = (t & 7) ^ (srow & 7);          // (row+64)&7 == row&7
  const char* aRow = (const char*)A + ((size_t)mt * 256 + srow) * Kb + sgr * 16;
  const char* bRow =
      (const char*)BT + ((size_t)e * N + n0 + srow) * Kb + sgr * 16;

  auto stageA = [&](int buf, int half, int kt) {
    char* dst =
        (char*)sm + (size_t)(buf * BUFSZ + half * (128 * 64)) * 2 + t * 16;
    const char* s = aRow + (size_t)(half * 128) * Kb + (size_t)kt * 128;
    async_cp16(dst, s);
    async_cp16(dst + 8192, s + 64 * Kb);
  };
  auto stageB = [&](int buf, int half, int kt) {
    char* dst = (char*)sm + (size_t)(buf * BUFSZ + ABUF + half * (HB * 64)) * 2 +
                t * 16;
    const char* s = bRow + (size_t)(half * HB) * Kb + (size_t)kt * 128;
    async_cp16(dst, s);
    if constexpr (LB == 2) async_cp16(dst + 8192, s + 64 * Kb);
  };

  f32x4 acc[2][2][MF][NF] = {};
  bf16x8 af[MF][2];        // A fragments, current quadrant (reused across 2 ph)
  bf16x8 bg[2][NF][2];     // B fragments, both halves live simultaneously
  const int nk = K >> 6;

#define READ_A(HALF)                                                          \
  {                                                                           \
    const char* ap = bufBase + (size_t)(HALF) * (128 * 64 * 2);               \
    _Pragma("unroll") for (int mf = 0; mf < MF; ++mf) {                       \
      const int row = wm2 * RPA + mf * 16 + lr;                               \
      _Pragma("unroll") for (int ks = 0; ks < 2; ++ks)                        \
          af[mf][ks] = *(const bf16x8*)(ap + row * 128 +                      \
                                        (((ks * 4 + lg) ^ (lr & 7)) << 4));   \
    }                                                                         \
  }
#define READ_B(Q, HALF)                                                       \
  {                                                                           \
    const char* bp =                                                          \
        bufBase + (size_t)ABUF * 2 + (size_t)(HALF) * (HB * 64 * 2);          \
    _Pragma("unroll") for (int nf = 0; nf < NF; ++nf) {                       \
      const int row = wn2 * RPB + nf * 16 + lr;                               \
      _Pragma("unroll") for (int ks = 0; ks < 2; ++ks)                        \
          bg[Q][nf][ks] = *(const bf16x8*)(bp + row * 128 +                   \
                                           (((ks * 4 + lg) ^ (lr & 7)) << 4)); \
    }                                                                         \
  }
#define MMA(QM, QN)                                                           \
  __builtin_amdgcn_s_setprio(1);                                              \
  _Pragma("unroll") for (int ks = 0; ks < 2; ++ks)                            \
      _Pragma("unroll") for (int mf = 0; mf < MF; ++mf)                       \
          _Pragma("unroll") for (int nf = 0; nf < NF; ++nf)                   \
              acc[QM][QN][mf][nf] = __builtin_amdgcn_mfma_f32_16x16x32_bf16(  \
                  af[mf][ks], bg[QN][nf][ks], acc[QM][QN][mf][nf], 0, 0, 0);  \
  __builtin_amdgcn_s_setprio(0);
#define BAR                                                                   \
  __builtin_amdgcn_s_barrier();                                               \
  asm volatile("" ::: "memory");

  // prologue: K-tile 0 complete + A0,B0 of K-tile 1 (stay in flight)
  stageA(0, 0, 0); stageB(0, 0, 0); stageA(0, 1, 0); stageB(0, 1, 0);
  stageA(1, 0, 1); stageB(1, 0, 1);
  if constexpr (LB == 2) asm volatile("s_waitcnt vmcnt(4)" ::: "memory");
  else                   asm volatile("s_waitcnt vmcnt(3)" ::: "memory");
  BAR;

  for (int kt = 0; kt < nk; ++kt) {
    const int bi = kt & 1;
    const char* bufBase = (const char*)sm + (size_t)bi * BUFSZ * 2;
    // P0
    READ_A(0);
    READ_B(0, 0);
    if (kt + 1 < nk) stageA(bi ^ 1, 1, kt + 1);
    BAR;
    MMA(0, 0);
    BAR;
    // P1
    READ_B(1, 1);
    if (kt + 1 < nk) stageB(bi ^ 1, 1, kt + 1);
    BAR;
    MMA(0, 1);
    BAR;
    // P2
    READ_A(1);
    if (kt + 2 < nk) stageA(bi, 0, kt + 2);
    BAR;
    MMA(1, 0);
    BAR;
    // P3
    if (kt + 2 < nk) stageB(bi, 0, kt + 2);
    BAR;
    MMA(1, 1);
    if (kt + 2 < nk) {
      if constexpr (LB == 2) asm volatile("s_waitcnt vmcnt(4)" ::: "memory");
      else                   asm volatile("s_waitcnt vmcnt(3)" ::: "memory");
    } else {
      asm volatile("s_waitcnt vmcnt(0)" ::: "memory");
    }
    BAR;
  }
#undef READ_A
#undef READ_B
#undef MMA
#undef BAR

  // epilogue — C/D mapping col=lane&15, row=(lane>>4)*4+reg (m89-verified)
  const size_t mrow0 = (size_t)mt * 256;
  const float* bp = bias + (size_t)e * N + n0;
  unsigned short* ho = (unsigned short*)Out;
  float* fo = (float*)Out;
#pragma unroll
  for (int qm = 0; qm < 2; ++qm)
#pragma unroll
    for (int mf = 0; mf < MF; ++mf) {
      const int row0 = qm * 128 + wm2 * RPA + mf * 16 + lg * 4;
#pragma unroll
      for (int qn = 0; qn < 2; ++qn)
#pragma unroll
        for (int nf = 0; nf < NF; ++nf) {
          const int col = qn * HB + wn2 * RPB + nf * 16 + lr;
          const float bv = bp[col];
#pragma unroll
          for (int r = 0; r < 4; ++r) {
            float v = acc[qm][qn][mf][nf][r] + bv;
            if (RELU) v = fmaxf(v, 0.f);
            const size_t o = (mrow0 + row0 + r) * (size_t)N + n0 + col;
            if (OUT_BF16) ho[o] = f2bf(v);
            else fo[o] = v;
          }
        }
    }
}

// ---------------------------------------------------------------------------
// Launch
// ---------------------------------------------------------------------------
extern "C" void kernel_launch(void* const* d_in, const int* in_sizes, int n_in,
                              void* d_out, int out_size, void* d_ws,
                              size_t ws_size, hipStream_t stream) {
  const float* x = (const float*)d_in[0];
  const int* view_ids = (const int*)d_in[1];
  const int* visit_ids = (const int*)d_in[2];
  const float* rview = (const float*)d_in[3];
  const float* rvisit = (const float*)d_in[4];
  const float* W1 = (const float*)d_in[5];
  const float* b1 = (const float*)d_in[6];
  const float* W2 = (const float*)d_in[7];
  const float* b2 = (const float*)d_in[8];
  float* out = (float*)d_out;

  char* ws = (char*)d_ws;
  int* top1 = (int*)ws;                                               //    64 B
  unsigned short* x_bf = (unsigned short*)(ws + 256);                 // 16 MiB
  unsigned short* w1t = (unsigned short*)(ws + 256 + 16777216L);      // 16 MiB
  unsigned short* w2t = (unsigned short*)(ws + 256 + 2 * 16777216L);  // 16 MiB
  unsigned short* h_bf = (unsigned short*)(ws + 256 + 3 * 16777216L); // 64 MiB

  router_kernel<<<1, 64, 0, stream>>>(view_ids, visit_ids, rview, rvisit, top1,
                                      out + (size_t)B_SZ * L_SZ * D_SZ);
  cast_x_kernel<<<8192, 256, 0, stream>>>(x, x_bf);
  transpose_cast_kernel<<<dim3(DFF_SZ / 64, D_SZ / 64, E_SZ), 256, 0, stream>>>(
      W1, w1t, D_SZ, DFF_SZ);
  transpose_cast_kernel<<<dim3(D_SZ / 64, DFF_SZ / 64, E_SZ), 256, 0, stream>>>(
      W2, w2t, DFF_SZ, D_SZ);

  // GEMM1: h = relu(x @ W1[e] + b1[e]) -> bf16.  M=16384, N=2048, K=512.
  gemm8_kernel<256, 4, 8, true, true><<<512, 512, 0, stream>>>(
      x_bf, w1t, b1, top1, (void*)h_bf, DFF_SZ, D_SZ);
  // GEMM2: out = h @ W2[e] + b2[e] -> f32.  M=16384, N=512, K=2048.
  gemm8_kernel<128, 2, 4, false, false><<<256, 512, 0, stream>>>(
      h_bf, w2t, b2, top1, (void*)out, D_SZ, DFF_SZ);
}

// Round 4
// 233.414 us; speedup vs baseline: 1.0931x; 1.0507x over previous
//
#include <hip/hip_runtime.h>
#include <stdint.h>

// Problem constants (reference file)
#define B_SZ 16
#define L_SZ 1024
#define D_SZ 512
#define E_SZ 8
#define DFF_SZ 2048

typedef short bf16x8 __attribute__((ext_vector_type(8)));
typedef float f32x4 __attribute__((ext_vector_type(4)));

__device__ __forceinline__ unsigned short f2bf(float f) {
  unsigned int u = __float_as_uint(f);
  u += 0x7fffu + ((u >> 16) & 1u);   // round-to-nearest-even
  return (unsigned short)(u >> 16);
}

__device__ __forceinline__ void async_cp16(void* lds, const void* g) {
  __builtin_amdgcn_global_load_lds(
      (const __attribute__((address_space(1))) void*)g,
      (__attribute__((address_space(3))) void*)lds, 16, 0, 0);
}

// ---------------------------------------------------------------------------
// Fused prep kernel: one dispatch replaces router + cast_x + 2 transposes.
// (stream-captured graphs are linear: separate dispatches serialize; fusing
//  removes 3 inter-kernel gaps and lets all prep work run concurrently)
//   blocks [0, 8192)        : cast x fp32->bf16 (float4/ushort4)
//   blocks [8192, 10240)    : W1 [E][D][DFF] -> [E][DFF][D] bf16
//   blocks [10240, 12288)   : W2 [E][DFF][D] -> [E][D][DFF] bf16
//   block  12288            : router top1 + balance loss
// ---------------------------------------------------------------------------
__device__ __forceinline__ void transpose_body(const float* __restrict__ src,
                                               unsigned short* __restrict__ dst,
                                               int K, int N, int bx, int by,
                                               int bz, float (*tile)[65]) {
  const int n0 = bx * 64;
  const int k0 = by * 64;
  const int t = threadIdx.x;          // 256
  {
    const int c4 = (t & 15) * 4;
    const int r = t >> 4;
    const float* s = src + ((size_t)bz * K + k0) * N + n0;
#pragma unroll
    for (int i = 0; i < 4; ++i) {
      const int k = r + i * 16;
      const float4 v = *(const float4*)(s + (size_t)k * N + c4);
      tile[k][c4] = v.x; tile[k][c4 + 1] = v.y;
      tile[k][c4 + 2] = v.z; tile[k][c4 + 3] = v.w;
    }
  }
  __syncthreads();
  {
    const int k4 = (t & 15) * 4;
    const int r = t >> 4;
    unsigned short* d = dst + ((size_t)bz * N + n0) * K + k0;
#pragma unroll
    for (int i = 0; i < 4; ++i) {
      const int n = r + i * 16;
      ushort4 o;
      o.x = f2bf(tile[k4 + 0][n]); o.y = f2bf(tile[k4 + 1][n]);
      o.z = f2bf(tile[k4 + 2][n]); o.w = f2bf(tile[k4 + 3][n]);
      *(ushort4*)(d + (size_t)n * K + k4) = o;
    }
  }
}

__global__ __launch_bounds__(256) void prep_kernel(
    const float* __restrict__ x, unsigned short* __restrict__ xb,
    const float* __restrict__ W1, unsigned short* __restrict__ w1t,
    const float* __restrict__ W2, unsigned short* __restrict__ w2t,
    const int* __restrict__ view_ids, const int* __restrict__ visit_ids,
    const float* __restrict__ rview, const float* __restrict__ rvisit,
    int* __restrict__ top1, float* __restrict__ loss_out) {
  __shared__ float tile[64][65];
  __shared__ float probs[B_SZ][E_SZ];
  const int b = blockIdx.x;
  if (b < 8192) {
    const int i = b * 256 + threadIdx.x;
    const float4 v = reinterpret_cast<const float4*>(x)[i];
    ushort4 o;
    o.x = f2bf(v.x); o.y = f2bf(v.y); o.z = f2bf(v.z); o.w = f2bf(v.w);
    reinterpret_cast<ushort4*>(xb)[i] = o;
  } else if (b < 10240) {
    const int i = b - 8192;  // W1 grid (32, 8, 8)
    transpose_body(W1, w1t, D_SZ, DFF_SZ, i & 31, (i >> 5) & 7, i >> 8, tile);
  } else if (b < 12288) {
    const int i = b - 10240;  // W2 grid (8, 32, 8)
    transpose_body(W2, w2t, DFF_SZ, D_SZ, i & 7, (i >> 3) & 31, i >> 8, tile);
  } else {
    const int t = threadIdx.x;
    if (t < B_SZ) {
      const int vi = view_ids[t];
      const int si = visit_ids[t];
      float lg[E_SZ];
#pragma unroll
      for (int e = 0; e < E_SZ; ++e)
        lg[e] = rview[vi * E_SZ + e] + rvisit[si * E_SZ + e];
      int am = 0;
      float bm = lg[0];
#pragma unroll
      for (int e = 1; e < E_SZ; ++e)
        if (lg[e] > bm) { bm = lg[e]; am = e; }
      top1[t] = am;
      float s = 0.f;
#pragma unroll
      for (int e = 0; e < E_SZ; ++e) {
        const float p = expf(lg[e] - bm);
        probs[t][e] = p;
        s += p;
      }
      const float inv = 1.f / s;
#pragma unroll
      for (int e = 0; e < E_SZ; ++e) probs[t][e] *= inv;
    }
    __syncthreads();
    if (t == 0) {
      float loss = 0.f;
#pragma unroll
      for (int e = 0; e < E_SZ; ++e) {
        float ld = 0.f;
        for (int bb = 0; bb < B_SZ; ++bb) ld += probs[bb][e];
        ld *= (1.0f / B_SZ);
        loss -= ld * logf(ld);
      }
      *loss_out = loss;
    }
  }
}

// ---------------------------------------------------------------------------
// Grouped bf16 MFMA GEMM — drift schedule: 2 barriers per K-tile (was 8).
//
// r3 post-mortem: 8 barriers/K-tile forced wave lockstep — all 8 waves issue
// ds_reads simultaneously (LDS saturated, MFMA idle) then all MFMA (LDS
// idle); reads+MFMA serialized -> MfmaUtil 25%. Hazard analysis shows only
// TWO collective points are needed per K-tile:
//   MID barrier: separates P0 reads of A0/B0(t) from P2/P3 stages of
//                A0/B0(t+2) into the same LDS slots (the only in-tile WAR).
//   END vmcnt(LA+LB)+barrier: collective "tile t+1 halves A1,B1 landed";
//                everything older (A0,B0(t+1)) retired transitively. RAW safe.
// Between barriers waves drift: one wave's ds_reads overlap another's MFMA
// (separate pipes), and setprio(1) favors the MFMA-issuing wave.
// B1-read hoisted into P0 so MMA(0,0) waits only its own 12 reads (counted
// lgkmcnt), B1's 4 drain under MMA(0,0). A1 stays at P2 (same af regs as A0
// — a 2nd af set would blow the 256-reg / 2-waves-per-SIMD budget).
// ---------------------------------------------------------------------------
template <int BN, int WN2, int NTILES, bool RELU, bool OUT_BF16>
__global__ __launch_bounds__(512, 2) void gemm8_kernel(
    const unsigned short* __restrict__ A,
    const unsigned short* __restrict__ BT,
    const float* __restrict__ bias,
    const int* __restrict__ top1,
    void* __restrict__ Out,
    int N, int K) {
  constexpr int HB = BN / 2;          // rows per B half
  constexpr int WM2 = 8 / WN2;        // wave grid inside a quadrant
  constexpr int RPA = 128 / WM2;      // A rows per wave in quadrant
  constexpr int RPB = HB / WN2;       // B rows per wave in quadrant
  constexpr int MF = RPA / 16;        // m fragments per wave per quadrant
  constexpr int NF = RPB / 16;        // n fragments
  constexpr int LB = HB / 64;         // global_load_lds per B half (A: 2)
  constexpr int ABUF = 2 * 128 * 64;  // elems (A region per buf)
  constexpr int BBUF = 2 * HB * 64;
  constexpr int BUFSZ = ABUF + BBUF;

  __shared__ __align__(16) unsigned short sm[2 * BUFSZ];

  const int t = threadIdx.x;
  const int lane = t & 63;
  const int wid = t >> 6;
  const int wm2 = wid / WN2;
  const int wn2 = wid % WN2;
  const int lr = lane & 15, lg = lane >> 4;

  // block mapping + XCD-aware swizzle (nwg % 8 == 0 in both instantiations)
  const int nwg = gridDim.x;
  const int bid = blockIdx.x;
  const int wg = (bid & 7) * (nwg >> 3) + (bid >> 3);
  const int mt = wg / NTILES;          // m-tile over B*L/256 = 64
  const int nt = wg % NTILES;
  const int n0 = nt * BN;
  const int bz = mt >> 2;              // 1024 rows per sample / 256
  const int e = top1[bz];

  // staging: thread t owns granule (row=t>>3, g=t&7); source granule is
  // pre-swizzled (g ^ row&7) so linear global_load_lds + swizzled ds_read match
  const size_t Kb = (size_t)K * 2;
  const int srow = t >> 3;                       // 0..63
  const int sgr = (t & 7) ^ (srow & 7);          // (row+64)&7 == row&7
  const char* aRow = (const char*)A + ((size_t)mt * 256 + srow) * Kb + sgr * 16;
  const char* bRow =
      (const char*)BT + ((size_t)e * N + n0 + srow) * Kb + sgr * 16;

  auto stageA = [&](int buf, int half, int kt) {
    char* dst =
        (char*)sm + (size_t)(buf * BUFSZ + half * (128 * 64)) * 2 + t * 16;
    const char* s = aRow + (size_t)(half * 128) * Kb + (size_t)kt * 128;
    async_cp16(dst, s);
    async_cp16(dst + 8192, s + 64 * Kb);
  };
  auto stageB = [&](int buf, int half, int kt) {
    char* dst = (char*)sm + (size_t)(buf * BUFSZ + ABUF + half * (HB * 64)) * 2 +
                t * 16;
    const char* s = bRow + (size_t)(half * HB) * Kb + (size_t)kt * 128;
    async_cp16(dst, s);
    if constexpr (LB == 2) async_cp16(dst + 8192, s + 64 * Kb);
  };

  f32x4 acc[2][2][MF][NF] = {};
  bf16x8 af[MF][2];        // A fragments (A0 then A1 — same regs, sequential)
  bf16x8 bg[2][NF][2];     // B fragments, both halves live simultaneously
  const int nk = K >> 6;

#define READ_A(HALF)                                                          \
  {                                                                           \
    const char* ap = bufBase + (size_t)(HALF) * (128 * 64 * 2);               \
    _Pragma("unroll") for (int mf = 0; mf < MF; ++mf) {                       \
      const int row = wm2 * RPA + mf * 16 + lr;                               \
      _Pragma("unroll") for (int ks = 0; ks < 2; ++ks)                        \
          af[mf][ks] = *(const bf16x8*)(ap + row * 128 +                      \
                                        (((ks * 4 + lg) ^ (lr & 7)) << 4));   \
    }                                                                         \
  }
#define READ_B(Q, HALF)                                                       \
  {                                                                           \
    const char* bp =                                                          \
        bufBase + (size_t)ABUF * 2 + (size_t)(HALF) * (HB * 64 * 2);          \
    _Pragma("unroll") for (int nf = 0; nf < NF; ++nf) {                       \
      const int row = wn2 * RPB + nf * 16 + lr;                               \
      _Pragma("unroll") for (int ks = 0; ks < 2; ++ks)                        \
          bg[Q][nf][ks] = *(const bf16x8*)(bp + row * 128 +                   \
                                           (((ks * 4 + lg) ^ (lr & 7)) << 4)); \
    }                                                                         \
  }
#define MMA(QM, QN)                                                           \
  __builtin_amdgcn_s_setprio(1);                                              \
  _Pragma("unroll") for (int ks = 0; ks < 2; ++ks)                            \
      _Pragma("unroll") for (int mf = 0; mf < MF; ++mf)                       \
          _Pragma("unroll") for (int nf = 0; nf < NF; ++nf)                   \
              acc[QM][QN][mf][nf] = __builtin_amdgcn_mfma_f32_16x16x32_bf16(  \
                  af[mf][ks], bg[QN][nf][ks], acc[QM][QN][mf][nf], 0, 0, 0);  \
  __builtin_amdgcn_s_setprio(0);
#define BAR                                                                   \
  __builtin_amdgcn_s_barrier();                                               \
  asm volatile("" ::: "memory");

  // prologue: K-tile 0 complete + A0,B0 of K-tile 1 (stay in flight)
  stageA(0, 0, 0); stageB(0, 0, 0); stageA(0, 1, 0); stageB(0, 1, 0);
  stageA(1, 0, 1); stageB(1, 0, 1);
  if constexpr (LB == 2) asm volatile("s_waitcnt vmcnt(4)" ::: "memory");
  else                   asm volatile("s_waitcnt vmcnt(3)" ::: "memory");
  BAR;

  for (int kt = 0; kt < nk; ++kt) {
    const int bi = kt & 1;
    const char* bufBase = (const char*)sm + (size_t)bi * BUFSZ * 2;
    // ---- first half-tile (P0+P1 region, no internal barrier: waves drift)
    READ_A(0);
    READ_B(0, 0);
    READ_B(1, 1);                       // hoisted: drains under MMA(0,0)
    if (kt + 1 < nk) stageA(bi ^ 1, 1, kt + 1);
    MMA(0, 0);
    if (kt + 1 < nk) stageB(bi ^ 1, 1, kt + 1);
    MMA(0, 1);
    BAR;  // MID: P0 reads of A0/B0(t) done before A0/B0 slots rewritten below
    // ---- second half-tile (P2+P3 region)
    READ_A(1);
    if (kt + 2 < nk) stageA(bi, 0, kt + 2);
    MMA(1, 0);
    if (kt + 2 < nk) stageB(bi, 0, kt + 2);
    MMA(1, 1);
    if (kt + 2 < nk) {
      if constexpr (LB == 2) asm volatile("s_waitcnt vmcnt(4)" ::: "memory");
      else                   asm volatile("s_waitcnt vmcnt(3)" ::: "memory");
    } else {
      asm volatile("s_waitcnt vmcnt(0)" ::: "memory");
    }
    BAR;  // END: collective "tile t+1 staged" (vmcnt above makes it so)
  }
#undef READ_A
#undef READ_B
#undef MMA
#undef BAR

  // epilogue — C/D mapping col=lane&15, row=(lane>>4)*4+reg (m89-verified)
  const size_t mrow0 = (size_t)mt * 256;
  const float* bp = bias + (size_t)e * N + n0;
  unsigned short* ho = (unsigned short*)Out;
  float* fo = (float*)Out;
#pragma unroll
  for (int qm = 0; qm < 2; ++qm)
#pragma unroll
    for (int mf = 0; mf < MF; ++mf) {
      const int row0 = qm * 128 + wm2 * RPA + mf * 16 + lg * 4;
#pragma unroll
      for (int qn = 0; qn < 2; ++qn)
#pragma unroll
        for (int nf = 0; nf < NF; ++nf) {
          const int col = qn * HB + wn2 * RPB + nf * 16 + lr;
          const float bv = bp[col];
#pragma unroll
          for (int r = 0; r < 4; ++r) {
            float v = acc[qm][qn][mf][nf][r] + bv;
            if (RELU) v = fmaxf(v, 0.f);
            const size_t o = (mrow0 + row0 + r) * (size_t)N + n0 + col;
            if (OUT_BF16) ho[o] = f2bf(v);
            else fo[o] = v;
          }
        }
    }
}

// ---------------------------------------------------------------------------
// Launch
// ---------------------------------------------------------------------------
extern "C" void kernel_launch(void* const* d_in, const int* in_sizes, int n_in,
                              void* d_out, int out_size, void* d_ws,
                              size_t ws_size, hipStream_t stream) {
  const float* x = (const float*)d_in[0];
  const int* view_ids = (const int*)d_in[1];
  const int* visit_ids = (const int*)d_in[2];
  const float* rview = (const float*)d_in[3];
  const float* rvisit = (const float*)d_in[4];
  const float* W1 = (const float*)d_in[5];
  const float* b1 = (const float*)d_in[6];
  const float* W2 = (const float*)d_in[7];
  const float* b2 = (const float*)d_in[8];
  float* out = (float*)d_out;

  char* ws = (char*)d_ws;
  int* top1 = (int*)ws;                                               //    64 B
  unsigned short* x_bf = (unsigned short*)(ws + 256);                 // 16 MiB
  unsigned short* w1t = (unsigned short*)(ws + 256 + 16777216L);      // 16 MiB
  unsigned short* w2t = (unsigned short*)(ws + 256 + 2 * 16777216L);  // 16 MiB
  unsigned short* h_bf = (unsigned short*)(ws + 256 + 3 * 16777216L); // 64 MiB

  // 1 fused prep dispatch (was 4): cast + both transposes + router
  prep_kernel<<<12289, 256, 0, stream>>>(
      x, x_bf, W1, w1t, W2, w2t, view_ids, visit_ids, rview, rvisit, top1,
      out + (size_t)B_SZ * L_SZ * D_SZ);

  // GEMM1: h = relu(x @ W1[e] + b1[e]) -> bf16.  M=16384, N=2048, K=512.
  gemm8_kernel<256, 4, 8, true, true><<<512, 512, 0, stream>>>(
      x_bf, w1t, b1, top1, (void*)h_bf, DFF_SZ, D_SZ);
  // GEMM2: out = h @ W2[e] + b2[e] -> f32.  M=16384, N=512, K=2048.
  gemm8_kernel<128, 2, 4, false, false><<<256, 512, 0, stream>>>(
      h_bf, w2t, b2, top1, (void*)out, D_SZ, DFF_SZ);
}